// Round 5
// baseline (352.162 us; speedup 1.0000x reference)
//
#include <hip/hip_runtime.h>
#include <hip/hip_bf16.h>

#define NIMG 256
#define CIN  256
#define PIX  784
#define DD   64
#define NP   200
#define NPP  208   // prototypes padded to 13*16
#define NCLS 10

#define XS 264     // row stride (bf16) xlds/w1lds: 132 dw; quad rotation for b128 reads
#define HS 72      // row stride (bf16) htile/ftile

typedef __attribute__((ext_vector_type(8))) short bf16x8;
typedef __attribute__((ext_vector_type(4))) float f32x4;
typedef __attribute__((ext_vector_type(4))) unsigned int u32x4;
typedef __attribute__((ext_vector_type(2))) unsigned int u32x2;

__device__ __forceinline__ unsigned short f2bf(float f) {
    union { float f; unsigned int u; } v; v.f = f;
    unsigned int r = v.u + 0x7fffu + ((v.u >> 16) & 1u);   // RNE
    return (unsigned short)(r >> 16);
}
__device__ __forceinline__ unsigned int pk2(float a, float b) {
    __hip_bfloat162 p = __float22bfloat162_rn(make_float2(a, b));
    return *(unsigned int*)&p;
}

#define MFMA(a, b, c) __builtin_amdgcn_mfma_f32_16x16x32_bf16((a), (b), (c), 0, 0, 0)

// LDS-only barrier: all cross-wave deps are through LDS; global prefetch
// loads stay in flight across barriers (essential for the depth-3 pipeline —
// __syncthreads() would emit vmcnt(0) and drain it every phase).
#define BARL() asm volatile("s_waitcnt lgkmcnt(0)\n\ts_barrier" ::: "memory")

// R5: identical to R4 except __launch_bounds__(1024, 4).
// R4's plain (1024) let the allocator cap at 64 VGPRs -> ~60 VGPRs of state
// spilled to scratch: WRITE_SIZE 216 KB -> 87.5 MB, FETCH +50 MB, and every
// store_st stalled on scratch reads. LDS (89.6 KB) forces 1 block/CU = 4
// waves/EU anyway, so declaring min 4 waves/EU raises the cap to 128 VGPRs
// (budget ~120) at zero occupancy cost.
__global__ __launch_bounds__(1024, 4)
void proto_fused_kernel(const float* __restrict__ x,
                        const float* __restrict__ W1, const float* __restrict__ b1,
                        const float* __restrict__ W2, const float* __restrict__ b2,
                        const float* __restrict__ proto,
                        const float* __restrict__ lastW, const float* __restrict__ lastb,
                        float* __restrict__ out)
{
    __shared__ __align__(16) unsigned short xlds[64 * XS];      // 33.8 KB, [px][c]
    __shared__ __align__(16) unsigned short w1lds[64 * XS];     // 33.8 KB, [o][c]
    __shared__ __align__(16) unsigned short htile[64 * HS];     //  9.2 KB, [px][d]
    __shared__ __align__(16) unsigned short ftile[64 * HS];     //  9.2 KB, [px][d]
    __shared__ float p2lds[NPP];
    __shared__ float s2lds[4][64];      // per-dt-quarter partial sums of f^2
    __shared__ float b1lds[DD], b2lds[DD];
    __shared__ unsigned int bmin[NPP];
    // total ~87 KB -> 1 block/CU (16 waves)

    const int n    = blockIdx.x;
    const int t    = threadIdx.x;
    const int lane = t & 63;
    const int q    = lane >> 4;     // quad row within wave
    const int l15  = lane & 15;
    const int wave = t >> 6;        // 0..15
    const int s    = wave & 3;      // pixel strip (16 px) within 64-px tile
    const int dt   = wave >> 2;     // this wave's d-tile / proto-tile group (0..3)

    // ---- x load lane map: 16 px-groups x 64 channel-groups (4 ch each) ----
    // per instr j: wave covers 4 channels x 64 px contiguous (4x256B runs).
    const int p4  = ((t >> 2) & 15) * 4;
    const int c4i = (t & 3) | ((t >> 6) << 2);   // 0..63
    const int c4  = c4i * 4;                     // channel base (4 ch/thread)
    const float* xn = x + (size_t)n * CIN * PIX;

    auto load_st = [&](float4 (&pf)[4], int st) {
        const int base = st * 64 + p4;
        #pragma unroll
        for (int j = 0; j < 4; ++j) {
            const float* src = xn + (size_t)(c4 + j) * PIX + base;
            float4 v;
            if (base + 3 < PIX) {
                v = *(const float4*)src;
            } else {
                v.x = (base + 0 < PIX) ? src[0] : 0.f;
                v.y = (base + 1 < PIX) ? src[1] : 0.f;
                v.z = (base + 2 < PIX) ? src[2] : 0.f;
                v.w = (base + 3 < PIX) ? src[3] : 0.f;
            }
            pf[j] = v;
        }
    };
    auto store_st = [&](float4 (&pf)[4]) {   // register transpose -> 4x ds_write_b64
        #pragma unroll
        for (int r = 0; r < 4; ++r) {
            u32x2 w;
            w.x = pk2(((const float*)&pf[0])[r], ((const float*)&pf[1])[r]);
            w.y = pk2(((const float*)&pf[2])[r], ((const float*)&pf[3])[r]);
            *(u32x2*)&xlds[(p4 + r) * XS + c4] = w;
        }
    };

    // issue 3 stages of x loads immediately (192 KB/CU in flight)
    float4 pfA[4], pfB[4], pfC[4];
    load_st(pfA, 0);
    load_st(pfB, 1);
    load_st(pfC, 2);

    // ---------------- one-time staging ----------------
    {   // W1: 64x256 fp32 = 4096 float4; 4 per thread
        const float4* W1v = (const float4*)W1;
        #pragma unroll
        for (int i = 0; i < 4; ++i) {
            int j = t + i * 1024;
            float4 v = W1v[j];
            u32x2 w;
            w.x = pk2(v.x, v.y); w.y = pk2(v.z, v.w);
            *(u32x2*)&w1lds[(j >> 6) * XS + (j & 63) * 4] = w;
        }
    }
    if (t < DD) { b1lds[t] = b1[t]; b2lds[t] = b2[t]; }
    if (t < NPP) {
        float acc = 0.f;
        if (t < NP) {
            const float4* pp = (const float4*)(proto + t * DD);
            #pragma unroll
            for (int i = 0; i < 16; ++i) {
                float4 v = pp[i];
                acc += v.x * v.x + v.y * v.y + v.z * v.z + v.w * v.w;
            }
        }
        p2lds[t] = acc;
        bmin[t] = 0x7f800000u;   // +inf bits (dist >= 0: uint order == float order)
    }

    // ---- W2 B-fragments straight from global (w2lds dropped) ----
    bf16x8 w2f[2];
    #pragma unroll
    for (int kk = 0; kk < 2; ++kk) {
        const float4* src = (const float4*)(W2 + (size_t)(dt * 16 + l15) * DD + kk * 32 + q * 8);
        float4 a = src[0], b = src[1];
        union { u32x4 u; bf16x8 h; } cv;
        cv.u.x = pk2(a.x, a.y); cv.u.y = pk2(a.z, a.w);
        cv.u.z = pk2(b.x, b.y); cv.u.w = pk2(b.z, b.w);
        w2f[kk] = cv.h;
    }

    // ---- prototype B-fragments from global: tiles pt = dt + 4*it ----
    bf16x8 pb0[4], pb1[4];
    #pragma unroll
    for (int it = 0; it < 4; ++it) {
        int pt = dt + 4 * it;                    // 0..15 (13..15 discarded)
        int p  = pt * 16 + l15;
        int pr = (p < NP) ? p : (NP - 1);        // clamp pads (results discarded)
        const float4* src = (const float4*)(proto + (size_t)pr * DD + q * 8);
        float4 a = src[0], b = src[1];           // k = q*8 .. q*8+7
        float4 c = src[8], d = src[9];           // k = 32 + q*8 ..
        union { u32x4 u; bf16x8 h; } cv0, cv1;
        cv0.u.x = pk2(a.x, a.y); cv0.u.y = pk2(a.z, a.w);
        cv0.u.z = pk2(b.x, b.y); cv0.u.w = pk2(b.z, b.w);
        cv1.u.x = pk2(c.x, c.y); cv1.u.y = pk2(c.z, c.w);
        cv1.u.z = pk2(d.x, d.y); cv1.u.w = pk2(d.z, d.w);
        pb0[it] = cv0.h; pb1[it] = cv1.h;
    }

    // prologue: stage 0 -> xlds (waits pfA; weight staging above gave slack),
    // then refill A with stage 3. In flight after this: B(1), C(2), A(3).
    store_st(pfA);
    load_st(pfA, 3);
    BARL();

    float p2r[4];
    #pragma unroll
    for (int it = 0; it < 4; ++it) {
        int pidx = (dt + 4 * it) * 16 + l15;
        p2r[it] = p2lds[pidx < NPP ? pidx : (NPP - 1)];
    }

    float rmin[4];
    #pragma unroll
    for (int it = 0; it < 4; ++it) rmin[it] = 1e30f;

    const int arow  = (s * 16 + l15) * XS + q * 8;
    const int wrow  = (dt * 16 + l15) * XS + q * 8;
    const int arowH = (s * 16 + l15) * HS + q * 8;
    const int bidx  = dt * 16 + l15;

    // one iteration; pf = buffer holding stage st+1 (stored here, refilled st+4)
    auto ITER = [&](int st, float4 (&pf)[4]) {
        // ---- P1: GEMM1 (xlds + w1lds) -> htile ----
        {
            f32x4 acc = {0.f, 0.f, 0.f, 0.f};
            #pragma unroll
            for (int kk = 0; kk < 8; ++kk) {
                bf16x8 a = *(const bf16x8*)&xlds[arow + kk * 32];
                bf16x8 w = *(const bf16x8*)&w1lds[wrow + kk * 32];
                acc = MFMA(a, w, acc);
            }
            #pragma unroll
            for (int r = 0; r < 4; ++r) {
                int prow = s * 16 + q * 4 + r;
                float h = fmaxf(acc[r] + b1lds[bidx], 0.f);
                htile[prow * HS + bidx] = f2bf(h);
            }
        }
        BARL();   // htile visibility; x prefetch (vmcnt) NOT drained

        // ---- P2: stage next x tile + refill prefetch; GEMM2 -> ftile, s2 ----
        if (st < 12) {
            store_st(pf);                 // counted vmcnt wait (3 iters of slack)
            if (st <= 8) load_st(pf, st + 4);
        }
        {
            f32x4 acc = {0.f, 0.f, 0.f, 0.f};
            bf16x8 a0 = *(const bf16x8*)&htile[arowH];
            bf16x8 a1 = *(const bf16x8*)&htile[arowH + 32];
            acc = MFMA(a0, w2f[0], acc);
            acc = MFMA(a1, w2f[1], acc);
            #pragma unroll
            for (int r = 0; r < 4; ++r) {
                int prow = s * 16 + q * 4 + r;
                float z = acc[r] + b2lds[bidx];
                float f = __builtin_amdgcn_rcpf(1.0f + __builtin_amdgcn_exp2f(z * -1.44269504f));
                ftile[prow * HS + bidx] = f2bf(f);
                float v = f * f;
                v += __shfl_xor(v, 1, 64);
                v += __shfl_xor(v, 2, 64);
                v += __shfl_xor(v, 4, 64);
                v += __shfl_xor(v, 8, 64);
                if (l15 == 0)
                    s2lds[dt][prow] = (st * 64 + prow < PIX) ? v : 1e30f;  // pad poison
            }
        }
        BARL();   // ftile/s2lds/xlds visibility; prefetch loads stay in flight

        // ---- P3: GEMM3 distances -> per-lane running min (regs only) ----
        {
            bf16x8 a0 = *(const bf16x8*)&ftile[arowH];
            bf16x8 a1 = *(const bf16x8*)&ftile[arowH + 32];
            float s2v[4];
            #pragma unroll
            for (int r = 0; r < 4; ++r) {
                int pl = s * 16 + q * 4 + r;
                s2v[r] = (s2lds[0][pl] + s2lds[1][pl]) + (s2lds[2][pl] + s2lds[3][pl]);
            }
            #pragma unroll
            for (int it = 0; it < 4; ++it) {
                int pt = dt + 4 * it;
                if (pt < 13) {                       // wave-uniform
                    f32x4 acc = {0.f, 0.f, 0.f, 0.f};
                    acc = MFMA(a0, pb0[it], acc);
                    acc = MFMA(a1, pb1[it], acc);
                    float m = 1e30f;
                    #pragma unroll
                    for (int r = 0; r < 4; ++r) {
                        float dist = fmaxf(s2v[r] - 2.f * acc[r] + p2r[it], 0.f);
                        m = fminf(m, dist);
                    }
                    rmin[it] = fminf(rmin[it], m);
                }
            }
        }
        // no barrier: next P1 reads xlds (stored pre-P2-barrier) + w1lds (const),
        // writes htile; P3 read only ftile/s2lds -> disjoint.
    };

    // 13 tiles; buffer rotation B,C,A matches "store stage st+1" mapping.
    for (int base = 0; base < 15; base += 3) {
        if (base + 0 < 13) ITER(base + 0, pfB);
        if (base + 1 < 13) ITER(base + 1, pfC);
        if (base + 2 < 13) ITER(base + 2, pfA);
    }

    // ---- final min reduction: regs -> bmin ----
    #pragma unroll
    for (int it = 0; it < 4; ++it) {
        int pt = dt + 4 * it;
        if (pt < 13) {
            float m = rmin[it];
            m = fminf(m, __shfl_xor(m, 16, 64));
            m = fminf(m, __shfl_xor(m, 32, 64));
            if (lane < 16) atomicMin(&bmin[pt * 16 + l15], __float_as_uint(m));
        }
    }
    BARL();   // ds_atomic visibility

    // ---------------- epilogue: min_distances + logits ----------------
    if (t < NP) {
        out[NIMG * NCLS + (size_t)n * NP + t] = __uint_as_float(bmin[t]);
    }
    if (t < 320) {
        int c = t >> 5, j = t & 31;
        float acc = 0.f;
        for (int p = j; p < NP; p += 32)
            acc += __uint_as_float(bmin[p]) * lastW[c * NP + p];
        acc += __shfl_xor(acc, 1, 32);
        acc += __shfl_xor(acc, 2, 32);
        acc += __shfl_xor(acc, 4, 32);
        acc += __shfl_xor(acc, 8, 32);
        acc += __shfl_xor(acc, 16, 32);
        if (j == 0) out[(size_t)n * NCLS + c] = -acc + lastb[c];
    }
}

extern "C" void kernel_launch(void* const* d_in, const int* in_sizes, int n_in,
                              void* d_out, int out_size, void* d_ws, size_t ws_size,
                              hipStream_t stream) {
    const float* x     = (const float*)d_in[0];
    const float* W1    = (const float*)d_in[1];
    const float* b1    = (const float*)d_in[2];
    const float* W2    = (const float*)d_in[3];
    const float* b2    = (const float*)d_in[4];
    const float* proto = (const float*)d_in[5];
    const float* lastW = (const float*)d_in[6];
    const float* lastb = (const float*)d_in[7];
    float* out = (float*)d_out;

    proto_fused_kernel<<<dim3(NIMG), dim3(1024), 0, stream>>>(
        x, W1, b1, W2, b2, proto, lastW, lastb, out);
}

// Round 6
// 308.314 us; speedup vs baseline: 1.1422x; 1.1422x over previous
//
#include <hip/hip_runtime.h>
#include <hip/hip_bf16.h>

#define NIMG 256
#define CIN  256
#define PIX  784
#define DD   64
#define NP   200
#define NPP  208   // prototypes padded to 13*16
#define NPT  13    // proto tiles actually used
#define NCLS 10

#define XS 264     // row stride (bf16) xlds/w1lds: 132 dw; quad rotation for b128 reads
#define HS 72      // row stride (bf16) htile/ftile

typedef __attribute__((ext_vector_type(8))) short bf16x8;
typedef __attribute__((ext_vector_type(4))) float f32x4;
typedef __attribute__((ext_vector_type(4))) unsigned int u32x4;
typedef __attribute__((ext_vector_type(2))) unsigned int u32x2;

__device__ __forceinline__ unsigned short f2bf(float f) {
    union { float f; unsigned int u; } v; v.f = f;
    unsigned int r = v.u + 0x7fffu + ((v.u >> 16) & 1u);   // RNE
    return (unsigned short)(r >> 16);
}
__device__ __forceinline__ unsigned int pk2(float a, float b) {
    __hip_bfloat162 p = __float22bfloat162_rn(make_float2(a, b));
    return *(unsigned int*)&p;
}

#define MFMA(a, b, c) __builtin_amdgcn_mfma_f32_16x16x32_bf16((a), (b), (c), 0, 0, 0)

// LDS-only barrier: all cross-wave deps are through LDS; global prefetch
// loads stay in flight across barriers.
#define BARL() asm volatile("s_waitcnt lgkmcnt(0)\n\ts_barrier" ::: "memory")

// R6: fit the 64-arch-VGPR reality of 1024-thread blocks (R4/R5: demand ~115
// -> ~50 regs spilled -> 87 MB scratch writes + 50 MB re-reads).
//  - pb fragments -> LDS (pblds, fragment-major, conflict-free b128 reads)
//  - prefetch depth 3 -> 2 (pfA/pfB)
//  - demand now ~65-70; (1024,1) as a cap-raise attempt (diagnostic only).
__global__ __launch_bounds__(1024, 1)
void proto_fused_kernel(const float* __restrict__ x,
                        const float* __restrict__ W1, const float* __restrict__ b1,
                        const float* __restrict__ W2, const float* __restrict__ b2,
                        const float* __restrict__ proto,
                        const float* __restrict__ lastW, const float* __restrict__ lastb,
                        float* __restrict__ out)
{
    __shared__ __align__(16) unsigned short xlds[64 * XS];          // 33.8 KB, [px][c]
    __shared__ __align__(16) unsigned short w1lds[64 * XS];         // 33.8 KB, [o][c]
    __shared__ __align__(16) unsigned short htile[64 * HS];         //  9.2 KB, [px][d]
    __shared__ __align__(16) unsigned short ftile[64 * HS];         //  9.2 KB, [px][d]
    __shared__ __align__(16) unsigned short pblds[NPT * 2 * 64 * 8];// 26.6 KB, [pt][half][q*16+l15][8]
    __shared__ float p2lds[NPP];
    __shared__ float s2lds[4][64];      // per-dt-quarter partial sums of f^2
    __shared__ float b1lds[DD], b2lds[DD];
    __shared__ unsigned int bmin[NPP];
    // total ~115.8 KB -> 1 block/CU (16 waves)

    const int n    = blockIdx.x;
    const int t    = threadIdx.x;
    const int lane = t & 63;
    const int q    = lane >> 4;     // quad row within wave
    const int l15  = lane & 15;
    const int wave = t >> 6;        // 0..15
    const int s    = wave & 3;      // pixel strip (16 px) within 64-px tile
    const int dt   = wave >> 2;     // this wave's d-tile / proto-tile group (0..3)

    // ---- x load lane map: 16 px-groups x 64 channel-groups (4 ch each) ----
    const int p4  = ((t >> 2) & 15) * 4;
    const int c4i = (t & 3) | ((t >> 6) << 2);   // 0..63
    const int c4  = c4i * 4;                     // channel base (4 ch/thread)
    const float* xn = x + (size_t)n * CIN * PIX;

    auto load_st = [&](float4 (&pf)[4], int st) {
        const int base = st * 64 + p4;
        #pragma unroll
        for (int j = 0; j < 4; ++j) {
            const float* src = xn + (size_t)(c4 + j) * PIX + base;
            float4 v;
            if (base + 3 < PIX) {
                v = *(const float4*)src;
            } else {
                v.x = (base + 0 < PIX) ? src[0] : 0.f;
                v.y = (base + 1 < PIX) ? src[1] : 0.f;
                v.z = (base + 2 < PIX) ? src[2] : 0.f;
                v.w = (base + 3 < PIX) ? src[3] : 0.f;
            }
            pf[j] = v;
        }
    };
    auto store_st = [&](float4 (&pf)[4]) {   // register transpose -> 4x ds_write_b64
        #pragma unroll
        for (int r = 0; r < 4; ++r) {
            u32x2 w;
            w.x = pk2(((const float*)&pf[0])[r], ((const float*)&pf[1])[r]);
            w.y = pk2(((const float*)&pf[2])[r], ((const float*)&pf[3])[r]);
            *(u32x2*)&xlds[(p4 + r) * XS + c4] = w;
        }
    };

    // issue 2 stages of x loads immediately (128 KB/CU in flight)
    float4 pfA[4], pfB[4];
    load_st(pfA, 0);
    load_st(pfB, 1);

    // ---------------- one-time staging ----------------
    {   // W1: 64x256 fp32 = 4096 float4; 4 per thread
        const float4* W1v = (const float4*)W1;
        #pragma unroll
        for (int i = 0; i < 4; ++i) {
            int j = t + i * 1024;
            float4 v = W1v[j];
            u32x2 w;
            w.x = pk2(v.x, v.y); w.y = pk2(v.z, v.w);
            *(u32x2*)&w1lds[(j >> 6) * XS + (j & 63) * 4] = w;
        }
    }
    {   // prototypes -> pblds fragment layout; 13312 = 13*1024 elements
        #pragma unroll
        for (int i = 0; i < 13; ++i) {
            int idx = t + i * 1024;
            int p = idx >> 6, k = idx & 63;
            float v = (p < NP) ? proto[p * DD + k] : 0.f;   // pad rows zero (discarded)
            int pt = p >> 4, l = p & 15, half = k >> 5, qq = (k & 31) >> 3, k7 = k & 7;
            if (pt < NPT)
                pblds[(((pt * 2 + half) * 4 + qq) * 16 + l) * 8 + k7] = f2bf(v);
        }
    }
    if (t < DD) { b1lds[t] = b1[t]; b2lds[t] = b2[t]; }
    if (t < NPP) {
        float acc = 0.f;
        if (t < NP) {
            const float4* pp = (const float4*)(proto + t * DD);
            #pragma unroll
            for (int i = 0; i < 16; ++i) {
                float4 v = pp[i];
                acc += v.x * v.x + v.y * v.y + v.z * v.z + v.w * v.w;
            }
        }
        p2lds[t] = acc;
        bmin[t] = 0x7f800000u;   // +inf bits (dist >= 0: uint order == float order)
    }

    // ---- W2 B-fragments straight from global (8 VGPRs) ----
    bf16x8 w2f[2];
    #pragma unroll
    for (int kk = 0; kk < 2; ++kk) {
        const float4* src = (const float4*)(W2 + (size_t)(dt * 16 + l15) * DD + kk * 32 + q * 8);
        float4 a = src[0], b = src[1];
        union { u32x4 u; bf16x8 h; } cv;
        cv.u.x = pk2(a.x, a.y); cv.u.y = pk2(a.z, a.w);
        cv.u.z = pk2(b.x, b.y); cv.u.w = pk2(b.z, b.w);
        w2f[kk] = cv.h;
    }

    // prologue: stage 0 -> xlds (waits pfA; staging above gave slack),
    // then refill A with stage 2. In flight after this: B(1), A(2).
    store_st(pfA);
    load_st(pfA, 2);
    BARL();

    float p2r[4];
    #pragma unroll
    for (int it = 0; it < 4; ++it) {
        int pidx = (dt + 4 * it) * 16 + l15;
        p2r[it] = p2lds[pidx < NPP ? pidx : (NPP - 1)];
    }

    float rmin[4];
    #pragma unroll
    for (int it = 0; it < 4; ++it) rmin[it] = 1e30f;

    const int arow  = (s * 16 + l15) * XS + q * 8;
    const int wrow  = (dt * 16 + l15) * XS + q * 8;
    const int arowH = (s * 16 + l15) * HS + q * 8;
    const int bidx  = dt * 16 + l15;
    const int pboff = (q * 16 + l15) * 8;     // lane offset within a (pt,half) panel

    // one iteration; pf = buffer holding stage st+1 (stored here, refilled st+3)
    auto ITER = [&](int st, float4 (&pf)[4]) {
        // ---- P1: GEMM1 (xlds + w1lds) -> htile ----
        {
            f32x4 acc = {0.f, 0.f, 0.f, 0.f};
            #pragma unroll
            for (int kk = 0; kk < 8; ++kk) {
                bf16x8 a = *(const bf16x8*)&xlds[arow + kk * 32];
                bf16x8 w = *(const bf16x8*)&w1lds[wrow + kk * 32];
                acc = MFMA(a, w, acc);
            }
            #pragma unroll
            for (int r = 0; r < 4; ++r) {
                int prow = s * 16 + q * 4 + r;
                float h = fmaxf(acc[r] + b1lds[bidx], 0.f);
                htile[prow * HS + bidx] = f2bf(h);
            }
        }
        BARL();   // htile visibility; x prefetch (vmcnt) NOT drained

        // ---- P2: stage next x tile + refill prefetch; GEMM2 -> ftile, s2 ----
        if (st < 12) {
            store_st(pf);                 // counted vmcnt wait (2 iters of slack)
            if (st <= 9) load_st(pf, st + 3);
        }
        {
            f32x4 acc = {0.f, 0.f, 0.f, 0.f};
            bf16x8 a0 = *(const bf16x8*)&htile[arowH];
            bf16x8 a1 = *(const bf16x8*)&htile[arowH + 32];
            acc = MFMA(a0, w2f[0], acc);
            acc = MFMA(a1, w2f[1], acc);
            #pragma unroll
            for (int r = 0; r < 4; ++r) {
                int prow = s * 16 + q * 4 + r;
                float z = acc[r] + b2lds[bidx];
                float f = __builtin_amdgcn_rcpf(1.0f + __builtin_amdgcn_exp2f(z * -1.44269504f));
                ftile[prow * HS + bidx] = f2bf(f);
                float v = f * f;
                v += __shfl_xor(v, 1, 64);
                v += __shfl_xor(v, 2, 64);
                v += __shfl_xor(v, 4, 64);
                v += __shfl_xor(v, 8, 64);
                if (l15 == 0)
                    s2lds[dt][prow] = (st * 64 + prow < PIX) ? v : 1e30f;  // pad poison
            }
        }
        BARL();   // ftile/s2lds/xlds visibility; prefetch loads stay in flight

        // ---- P3: GEMM3 distances -> per-lane running min (regs only) ----
        {
            bf16x8 a0 = *(const bf16x8*)&ftile[arowH];
            bf16x8 a1 = *(const bf16x8*)&ftile[arowH + 32];
            float s2v[4];
            #pragma unroll
            for (int r = 0; r < 4; ++r) {
                int pl = s * 16 + q * 4 + r;
                s2v[r] = (s2lds[0][pl] + s2lds[1][pl]) + (s2lds[2][pl] + s2lds[3][pl]);
            }
            #pragma unroll
            for (int it = 0; it < 4; ++it) {
                int pt = dt + 4 * it;
                if (pt < NPT) {                      // wave-uniform
                    bf16x8 b0 = *(const bf16x8*)&pblds[(pt * 2 + 0) * 512 + pboff];
                    bf16x8 b1v = *(const bf16x8*)&pblds[(pt * 2 + 1) * 512 + pboff];
                    f32x4 acc = {0.f, 0.f, 0.f, 0.f};
                    acc = MFMA(a0, b0, acc);
                    acc = MFMA(a1, b1v, acc);
                    float m = 1e30f;
                    #pragma unroll
                    for (int r = 0; r < 4; ++r) {
                        float dist = fmaxf(s2v[r] - 2.f * acc[r] + p2r[it], 0.f);
                        m = fminf(m, dist);
                    }
                    rmin[it] = fminf(rmin[it], m);
                }
            }
        }
        // no barrier: next P1 reads xlds (stored pre-P2-barrier) + w1lds (const),
        // writes htile; P3 read only ftile/s2lds/pblds -> disjoint.
    };

    // 13 tiles; even st -> pfB (holds st+1), odd st -> pfA.
    for (int stp = 0; stp < 13; stp += 2) {
        ITER(stp, pfB);
        if (stp + 1 < 13) ITER(stp + 1, pfA);
    }

    // ---- final min reduction: regs -> bmin ----
    #pragma unroll
    for (int it = 0; it < 4; ++it) {
        int pt = dt + 4 * it;
        if (pt < NPT) {
            float m = rmin[it];
            m = fminf(m, __shfl_xor(m, 16, 64));
            m = fminf(m, __shfl_xor(m, 32, 64));
            if (lane < 16) atomicMin(&bmin[pt * 16 + l15], __float_as_uint(m));
        }
    }
    BARL();   // ds_atomic visibility

    // ---------------- epilogue: min_distances + logits ----------------
    if (t < NP) {
        out[NIMG * NCLS + (size_t)n * NP + t] = __uint_as_float(bmin[t]);
    }
    if (t < 320) {
        int c = t >> 5, j = t & 31;
        float acc = 0.f;
        for (int p = j; p < NP; p += 32)
            acc += __uint_as_float(bmin[p]) * lastW[c * NP + p];
        acc += __shfl_xor(acc, 1, 32);
        acc += __shfl_xor(acc, 2, 32);
        acc += __shfl_xor(acc, 4, 32);
        acc += __shfl_xor(acc, 8, 32);
        acc += __shfl_xor(acc, 16, 32);
        if (j == 0) out[(size_t)n * NCLS + c] = -acc + lastb[c];
    }
}

extern "C" void kernel_launch(void* const* d_in, const int* in_sizes, int n_in,
                              void* d_out, int out_size, void* d_ws, size_t ws_size,
                              hipStream_t stream) {
    const float* x     = (const float*)d_in[0];
    const float* W1    = (const float*)d_in[1];
    const float* b1    = (const float*)d_in[2];
    const float* W2    = (const float*)d_in[3];
    const float* b2    = (const float*)d_in[4];
    const float* proto = (const float*)d_in[5];
    const float* lastW = (const float*)d_in[6];
    const float* lastb = (const float*)d_in[7];
    float* out = (float*)d_out;

    proto_fused_kernel<<<dim3(NIMG), dim3(1024), 0, stream>>>(
        x, W1, b1, W2, b2, proto, lastW, lastb, out);
}